// Round 23
// baseline (224.965 us; speedup 1.0000x reference)
//
#include <hip/hip_runtime.h>
#include <hip/hip_fp16.h>
#include <hip/hip_cooperative_groups.h>

namespace cg = cooperative_groups;

#define NG 128
#define CHUNK 4096

__device__ __forceinline__ int wave_iscan(int v, int lane) {
#pragma unroll
  for (int off = 1; off < 64; off <<= 1) {
    int u = __shfl_up(v, off, 64);
    if (lane >= off) v += u;
  }
  return v;
}

// ---- fused CSR build: hist + scan + partition + counting sort -----------
// Cooperative kernel, grid = max(nblkE, K) blocks (both <= 256, co-resident).
__global__ void coop_csr_kernel(const int* __restrict__ ei, int E, int K, int nblkE,
                                int* __restrict__ off, int* __restrict__ rowsum,
                                int* __restrict__ bbase, const float* __restrict__ x,
                                int* __restrict__ deg, int* __restrict__ rowptr,
                                float* __restrict__ dis, float* __restrict__ xs,
                                unsigned short* __restrict__ esrc,
                                unsigned int* __restrict__ epack, int N) {
  cg::grid_group grid = cg::this_grid();
  __shared__ int lh[256];
  __shared__ int lcur[256];
  __shared__ int wsum[4];
  int tid = threadIdx.x, bid = blockIdx.x;
  int lane = tid & 63, wid = tid >> 6;

  // ---- phase 1: per-chunk histogram -> off[q*nblkE + bid] ----
  if (bid < nblkE) {
    lh[tid] = 0;
    __syncthreads();
    int e0 = bid * CHUNK;
    const int4* d4 = (const int4*)(ei + E + e0);
    for (int i = tid; i < CHUNK / 4; i += 256) {
      int base = e0 + 4 * i;
      if (base + 3 < E) {
        int4 d = d4[i];
        atomicAdd(&lh[d.x >> 8], 1);
        atomicAdd(&lh[d.y >> 8], 1);
        atomicAdd(&lh[d.z >> 8], 1);
        atomicAdd(&lh[d.w >> 8], 1);
      } else {
#pragma unroll
        for (int j = 0; j < 4; ++j) {
          int e = base + j;
          if (e < E) atomicAdd(&lh[ei[E + e] >> 8], 1);
        }
      }
    }
    __syncthreads();
    if (tid < K) off[tid * nblkE + bid] = lh[tid];
  }
  grid.sync();

  // ---- phase 2a: rowsum[b] = sum of bucket b's row ----
  if (bid < K) {
    int v = (tid < nblkE) ? off[bid * nblkE + tid] : 0;
#pragma unroll
    for (int o = 1; o < 64; o <<= 1) v += __shfl_xor(v, o, 64);
    if (lane == 0) wsum[wid] = v;
    __syncthreads();
    if (tid == 0) rowsum[bid] = wsum[0] + wsum[1] + wsum[2] + wsum[3];
  }
  grid.sync();

  // ---- phase 2b: block 0 scans rowsum -> bbase; bbase[K] = E ----
  if (bid == 0) {
    int v = (tid < K) ? rowsum[tid] : 0;
    int inc = wave_iscan(v, lane);
    if (lane == 63) wsum[wid] = inc;
    __syncthreads();
    if (tid == 0) {
      int a = 0;
#pragma unroll
      for (int w = 0; w < 4; ++w) { int t = wsum[w]; wsum[w] = a; a += t; }
      bbase[K] = E;
    }
    __syncthreads();
    if (tid < K) bbase[tid] = inc - v + wsum[wid];
  }
  grid.sync();

  // ---- phase 2c: exclusive scan of row b, + bbase[b] (absolute cursors) ----
  if (bid < K) {
    int v = (tid < nblkE) ? off[bid * nblkE + tid] : 0;
    int inc = wave_iscan(v, lane);
    if (lane == 63) wsum[wid] = inc;
    __syncthreads();
    if (tid == 0) {
      int a = bbase[bid];
#pragma unroll
      for (int w = 0; w < 4; ++w) { int t = wsum[w]; wsum[w] = a; a += t; }
    }
    __syncthreads();
    if (tid < nblkE) off[bid * nblkE + tid] = inc - v + wsum[wid];
  }
  grid.sync();

  // ---- phase 3: partition chunk -> epack runs ----
  if (bid < nblkE) {
    if (tid < K) lcur[tid] = off[tid * nblkE + bid];
    __syncthreads();
    int e0 = bid * CHUNK;
    const int4* s4 = (const int4*)(ei + e0);
    const int4* d4 = (const int4*)(ei + E + e0);
    for (int i = tid; i < CHUNK / 4; i += 256) {
      int base = e0 + 4 * i;
      if (base + 3 < E) {
        int4 s = s4[i];
        int4 d = d4[i];
#pragma unroll
        for (int j = 0; j < 4; ++j) {
          unsigned int ss = (unsigned int)((j == 0) ? s.x : (j == 1) ? s.y : (j == 2) ? s.z : s.w);
          unsigned int dd = (unsigned int)((j == 0) ? d.x : (j == 1) ? d.y : (j == 2) ? d.z : d.w);
          int pos = atomicAdd(&lcur[dd >> 8], 1);
          epack[pos] = (ss << 8) | (dd & 255u);
        }
      } else {
#pragma unroll
        for (int j = 0; j < 4; ++j) {
          int e = base + j;
          if (e < E) {
            unsigned int ss = (unsigned int)ei[e], dd = (unsigned int)ei[E + e];
            int pos = atomicAdd(&lcur[dd >> 8], 1);
            epack[pos] = (ss << 8) | (dd & 255u);
          }
        }
      }
    }
  }
  grid.sync();

  // ---- phase 4: per-bucket counting sort -> rowptr/deg/dis/xs, esrc ----
  if (bid < K) {
    lh[tid] = 0;
    __syncthreads();
    int be0 = bbase[bid];
    int be1 = bbase[bid + 1];
    for (int i = be0 + tid; i < be1; i += 256) atomicAdd(&lh[epack[i] & 255u], 1);
    __syncthreads();
    int v = lh[tid];
    int inc = wave_iscan(v, lane);
    if (lane == 63) wsum[wid] = inc;
    __syncthreads();
    if (tid == 0) {
      int a = be0;
#pragma unroll
      for (int w = 0; w < 4; ++w) { int t = wsum[w]; wsum[w] = a; a += t; }
    }
    __syncthreads();
    int exc = inc - v + wsum[wid];
    lcur[tid] = exc;
    int node = (bid << 8) + tid;
    if (node < N) {
      rowptr[node] = exc;
      deg[node] = v;
      float di = rsqrtf((float)v + 1.0f);  // +1 self loop
      dis[node] = di;
      float4 xv = ((const float4*)x)[node];
      ((float4*)xs)[node] = make_float4(di * xv.x, di * xv.y, di * xv.z, di * xv.w);
    }
    __syncthreads();
    for (int i = be0 + tid; i < be1; i += 256) {
      unsigned int pk = epack[i];
      int pos = atomicAdd(&lcur[pk & 255u], 1);
      esrc[pos] = (unsigned short)(pk >> 8);
    }
  }
}

// ---- layer 1 fused: wave per node; gather xs; h1p = fp16(dis*relu(a@W1+b1))
__global__ void __launch_bounds__(256, 8)
l1_kernel(const int* __restrict__ rowptr, const int* __restrict__ deg,
          const unsigned short* __restrict__ esrc, const float* __restrict__ xs,
          const float* __restrict__ x, const float* __restrict__ dis,
          const float* __restrict__ W1, const float* __restrict__ b1,
          __half* __restrict__ h1p, int N) {
  int tid = threadIdx.x;
  int lane = tid & 63, wid = tid >> 6;
  int d = __builtin_amdgcn_readfirstlane(blockIdx.x * 4 + wid);
  if (d >= N) return;
  float di = dis[d];
  int p = __builtin_amdgcn_readfirstlane(rowptr[d]);
  int n = __builtin_amdgcn_readfirstlane(deg[d]);
  float a0 = 0.f, a1 = 0.f, a2 = 0.f, a3 = 0.f;
  for (int k = lane; k < n; k += 64) {
    int e = esrc[p + k];
    float4 v = ((const float4*)xs)[e];
    a0 += v.x; a1 += v.y; a2 += v.z; a3 += v.w;
  }
  if (lane == 0) {  // self loop: + di*x[d]
    float4 xv = ((const float4*)x)[d];
    a0 = fmaf(di, xv.x, a0); a1 = fmaf(di, xv.y, a1);
    a2 = fmaf(di, xv.z, a2); a3 = fmaf(di, xv.w, a3);
  }
#pragma unroll
  for (int off = 1; off < 64; off <<= 1) {
    a0 += __shfl_xor(a0, off, 64);
    a1 += __shfl_xor(a1, off, 64);
    a2 += __shfl_xor(a2, off, 64);
    a3 += __shfl_xor(a3, off, 64);
  }
  a0 *= di; a1 *= di; a2 *= di; a3 *= di;
  float o = b1[lane] + a0 * W1[lane] + a1 * W1[64 + lane] + a2 * W1[128 + lane] + a3 * W1[192 + lane];
  h1p[(size_t)d * 64 + lane] = __float2half(di * fmaxf(o, 0.0f));
}

// ---- layer 2: grouped row-gather (8 edges/VMEM-round) + matmul + pool ----
__global__ void __launch_bounds__(256, 8)
l2_kernel(const int* __restrict__ rowptr, const int* __restrict__ deg,
          const unsigned short* __restrict__ esrc, const __half* __restrict__ h1p,
          const float* __restrict__ dis, const float* __restrict__ W2,
          const float* __restrict__ b2, const int* __restrict__ batch,
          float* __restrict__ gsum, int N) {
  __shared__ __align__(16) unsigned short ebuf[4][64];
  __shared__ float vbuf[4][64];
  __shared__ float obuf[4][64];
  __shared__ int gbuf[4];
  int tid = threadIdx.x;
  int lane = tid & 63, wid = tid >> 6;
  int g = lane >> 3, c = lane & 7;
  int d0 = blockIdx.x * 4 + wid;
  bool valid = d0 < N;
  int d = __builtin_amdgcn_readfirstlane(valid ? d0 : N - 1);
  float di = dis[d];
  int p = __builtin_amdgcn_readfirstlane(rowptr[d]);
  int n = __builtin_amdgcn_readfirstlane(deg[d]);
  float a0, a1, a2, a3, a4, a5, a6, a7;
  {  // self loop: only group 0 contributes it
    float ms = (g == 0) ? 1.0f : 0.0f;
    uint4 w = *(const uint4*)(h1p + (size_t)d * 64 + 8 * c);
    float2 f0 = __half22float2(*(__half2*)&w.x);
    float2 f1 = __half22float2(*(__half2*)&w.y);
    float2 f2 = __half22float2(*(__half2*)&w.z);
    float2 f3 = __half22float2(*(__half2*)&w.w);
    a0 = ms * f0.x; a1 = ms * f0.y; a2 = ms * f1.x; a3 = ms * f1.y;
    a4 = ms * f2.x; a5 = ms * f2.y; a6 = ms * f3.x; a7 = ms * f3.y;
  }
  for (int base = 0; base < n; base += 64) {
    int m64 = n - base;
    if (m64 > 64) m64 = 64;
    ebuf[wid][lane] = esrc[p + base + ((lane < m64) ? lane : (m64 - 1))];
    for (int k = 0; k < m64; k += 8) {
      int e = ebuf[wid][k + g];              // same-addr broadcast per group
      float m = (k + g < m64) ? 1.0f : 0.0f;
      uint4 w = *(const uint4*)(h1p + (size_t)e * 64 + 8 * c);
      float2 f0 = __half22float2(*(__half2*)&w.x);
      float2 f1 = __half22float2(*(__half2*)&w.y);
      float2 f2 = __half22float2(*(__half2*)&w.z);
      float2 f3 = __half22float2(*(__half2*)&w.w);
      a0 = fmaf(m, f0.x, a0); a1 = fmaf(m, f0.y, a1);
      a2 = fmaf(m, f1.x, a2); a3 = fmaf(m, f1.y, a3);
      a4 = fmaf(m, f2.x, a4); a5 = fmaf(m, f2.y, a5);
      a6 = fmaf(m, f3.x, a6); a7 = fmaf(m, f3.y, a7);
    }
  }
#pragma unroll
  for (int off = 8; off < 64; off <<= 1) {
    a0 += __shfl_xor(a0, off, 64); a1 += __shfl_xor(a1, off, 64);
    a2 += __shfl_xor(a2, off, 64); a3 += __shfl_xor(a3, off, 64);
    a4 += __shfl_xor(a4, off, 64); a5 += __shfl_xor(a5, off, 64);
    a6 += __shfl_xor(a6, off, 64); a7 += __shfl_xor(a7, off, 64);
  }
  if (g == 0) {
    *(float4*)&vbuf[wid][8 * c] = make_float4(di * a0, di * a1, di * a2, di * a3);
    *(float4*)&vbuf[wid][8 * c + 4] = make_float4(di * a4, di * a5, di * a6, di * a7);
  }
  float o = b2[lane];
  const float4* vb4 = (const float4*)vbuf[wid];
#pragma unroll
  for (int kk = 0; kk < 16; ++kk) {
    float4 vv = vb4[kk];
    o = fmaf(vv.x, W2[(kk * 4 + 0) * 64 + lane], o);
    o = fmaf(vv.y, W2[(kk * 4 + 1) * 64 + lane], o);
    o = fmaf(vv.z, W2[(kk * 4 + 2) * 64 + lane], o);
    o = fmaf(vv.w, W2[(kk * 4 + 3) * 64 + lane], o);
  }
  obuf[wid][lane] = fmaxf(o, 0.0f);
  if (lane == 0) gbuf[wid] = valid ? batch[d] : -1;
  __syncthreads();
  if (wid == 0) {
    float s = 0.0f;
    int cur = gbuf[0];
#pragma unroll
    for (int r = 0; r < 4; ++r) {
      int gg = gbuf[r];
      if (gg != cur) {
        if (cur >= 0) atomicAdd(&gsum[cur * 64 + lane], s);
        s = 0.0f;
        cur = gg;
      }
      if (gg >= 0) s += obuf[r][lane];
    }
    if (cur >= 0) atomicAdd(&gsum[cur * 64 + lane], s);
  }
}

// ---- output: mean via binary search on sorted batch ---------------------

__device__ __forceinline__ int lbound(const int* __restrict__ a, int n, int v) {
  int lo = 0, hi = n;
  while (lo < hi) {
    int mid = (lo + hi) >> 1;
    if (a[mid] < v) lo = mid + 1; else hi = mid;
  }
  return lo;
}

__global__ void out_kernel(const float* __restrict__ gsum, const int* __restrict__ batch,
                           int N, float* __restrict__ out) {
  int t = blockIdx.x * blockDim.x + threadIdx.x;
  if (t >= NG * 64) return;
  int g = t >> 6;
  int cnt = lbound(batch, N, g + 1) - lbound(batch, N, g);
  out[t] = gsum[t] / fmaxf((float)cnt, 1.0f);
}

// ---- launch --------------------------------------------------------------

extern "C" void kernel_launch(void* const* d_in, const int* in_sizes, int n_in,
                              void* d_out, int out_size, void* d_ws, size_t ws_size,
                              hipStream_t stream) {
  const float* x = (const float*)d_in[0];
  const int* ei = (const int*)d_in[1];     // [2,E]: src row then dst row
  const int* batch = (const int*)d_in[2];  // sorted graph ids
  const float* W1 = (const float*)d_in[4];
  const float* b1 = (const float*)d_in[5];
  const float* W2 = (const float*)d_in[6];
  const float* b2 = (const float*)d_in[7];

  const int N = in_sizes[0] / 4;           // 50000 (< 65536: ushort esrc ok)
  const int E = in_sizes[1] / 2;
  const int K = (N + 255) >> 8;                 // buckets (dst>>8), <= 256
  const int nblkE = (E + CHUNK - 1) / CHUNK;    // edge chunks, <= 256
  const int GRID = (K > nblkE) ? K : nblkE;
  const int M2 = K * nblkE;

  // ws layout (4B words unless noted):
  // [gsum 8192] <- zeroed each call
  // [rowsum 256][bbase 260][deg N][rowptr N][xs 4N][dis N][h1p 64N halves]
  // [esrc E ushorts][off M2][epack E words]
  float* gsum = (float*)d_ws;
  int* rowsum = (int*)(gsum + 64 * NG);
  int* bbase = rowsum + 256;
  int* deg = bbase + 260;
  int* rowptr = deg + N;
  float* xs = (float*)(rowptr + N);             // (8708+2N)%4==0 -> 16B aligned
  float* dis = xs + (size_t)4 * N;
  __half* h1p = (__half*)(dis + N);
  unsigned short* esrc = (unsigned short*)(dis + N + (size_t)32 * N);
  int* off = (int*)(esrc + E);                  // E even -> 4B aligned
  unsigned int* epack = (unsigned int*)(off + M2);

  hipMemsetAsync(d_ws, 0, (size_t)64 * NG * 4, stream);

  const int B = 256;
  {
    // non-const locals for the args array
    int E_ = E, K_ = K, nblkE_ = nblkE, N_ = N;
    const int* ei_ = ei;
    const float* x_ = x;
    void* args[] = {(void*)&ei_, (void*)&E_, (void*)&K_, (void*)&nblkE_,
                    (void*)&off, (void*)&rowsum, (void*)&bbase, (void*)&x_,
                    (void*)&deg, (void*)&rowptr, (void*)&dis, (void*)&xs,
                    (void*)&esrc, (void*)&epack, (void*)&N_};
    hipLaunchCooperativeKernel((const void*)coop_csr_kernel, dim3(GRID), dim3(256),
                               args, 0, stream);
  }
  l1_kernel<<<(N + 3) / 4, 256, 0, stream>>>(rowptr, deg, esrc, xs, x, dis, W1, b1, h1p, N);
  l2_kernel<<<(N + 3) / 4, 256, 0, stream>>>(rowptr, deg, esrc, h1p, dis, W2, b2, batch, gsum, N);
  out_kernel<<<(NG * 64 + B - 1) / B, B, 0, stream>>>(gsum, batch, N, (float*)d_out);
}

// Round 24
// 106.251 us; speedup vs baseline: 2.1173x; 2.1173x over previous
//
#include <hip/hip_runtime.h>
#include <hip/hip_fp16.h>

#define NG 128
#define CHUNK 4096

__device__ __forceinline__ int wave_iscan(int v, int lane) {
#pragma unroll
  for (int off = 1; off < 64; off <<= 1) {
    int u = __shfl_up(v, off, 64);
    if (lane >= off) v += u;
  }
  return v;
}

// ---- hist: per-chunk int4 histogram -> off matrix + global bucket totals --
__global__ void hist_kernel(const int* __restrict__ ei, int E, int nblkE, int K,
                            int* __restrict__ off, int* __restrict__ gcnt) {
  __shared__ int lh[256];
  int tid = threadIdx.x, blk = blockIdx.x;
  lh[tid] = 0;
  __syncthreads();
  int e0 = blk * CHUNK;
  const int4* d4 = (const int4*)(ei + E + e0);
  for (int i = tid; i < CHUNK / 4; i += 256) {
    int base = e0 + 4 * i;
    if (base + 3 < E) {
      int4 d = d4[i];
      atomicAdd(&lh[d.x >> 8], 1);
      atomicAdd(&lh[d.y >> 8], 1);
      atomicAdd(&lh[d.z >> 8], 1);
      atomicAdd(&lh[d.w >> 8], 1);
    } else {
#pragma unroll
      for (int j = 0; j < 4; ++j) {
        int e = base + j;
        if (e < E) atomicAdd(&lh[ei[E + e] >> 8], 1);
      }
    }
  }
  __syncthreads();
  if (tid < K) {
    int c = lh[tid];
    off[tid * nblkE + blk] = c;
    if (c) atomicAdd(&gcnt[tid], c);
  }
}

// ---- scan K bucket totals (K <= 256) -> bbase, bcur ---------------------
__global__ void scanK_kernel(const int* __restrict__ gcnt, int* __restrict__ bbase,
                             int* __restrict__ bcur, int K) {
  __shared__ int wsum[4];
  int tid = threadIdx.x;  // 256 threads
  int lane = tid & 63, wid = tid >> 6;
  int v = (tid < K) ? gcnt[tid] : 0;
  int inc = wave_iscan(v, lane);
  if (lane == 63) wsum[wid] = inc;
  __syncthreads();
  if (tid == 0) {
    int a = 0;
#pragma unroll
    for (int w = 0; w < 4; ++w) { int t = wsum[w]; wsum[w] = a; a += t; }
  }
  __syncthreads();
  if (tid < K) {
    int exc = inc - v + wsum[wid];
    bbase[tid] = exc;
    bcur[tid] = exc;
  }
}

// ---- partition: reserve runs from off column (no re-histogram), then one
// int4 edge pass writing epack = (src<<8)|(dst&255) into reserved runs ----
__global__ void part_kernel(const int* __restrict__ ei, int E, int nblkE, int K,
                            const int* __restrict__ off, int* __restrict__ bcur,
                            unsigned int* __restrict__ epack) {
  __shared__ int lcur[256];
  int tid = threadIdx.x, blk = blockIdx.x;
  if (tid < K) {
    int c = off[tid * nblkE + blk];
    lcur[tid] = c ? atomicAdd(&bcur[tid], c) : 0;
  }
  __syncthreads();
  int e0 = blk * CHUNK;
  const int4* s4 = (const int4*)(ei + e0);
  const int4* d4 = (const int4*)(ei + E + e0);
  for (int i = tid; i < CHUNK / 4; i += 256) {
    int base = e0 + 4 * i;
    if (base + 3 < E) {
      int4 s = s4[i];
      int4 d = d4[i];
#pragma unroll
      for (int j = 0; j < 4; ++j) {
        unsigned int ss = (unsigned int)((j == 0) ? s.x : (j == 1) ? s.y : (j == 2) ? s.z : s.w);
        unsigned int dd = (unsigned int)((j == 0) ? d.x : (j == 1) ? d.y : (j == 2) ? d.z : d.w);
        int pos = atomicAdd(&lcur[dd >> 8], 1);
        epack[pos] = (ss << 8) | (dd & 255u);
      }
    } else {
#pragma unroll
      for (int j = 0; j < 4; ++j) {
        int e = base + j;
        if (e < E) {
          unsigned int ss = (unsigned int)ei[e], dd = (unsigned int)ei[E + e];
          int pos = atomicAdd(&lcur[dd >> 8], 1);
          epack[pos] = (ss << 8) | (dd & 255u);
        }
      }
    }
  }
}

// one block per bucket: degree count + scan -> rowptr/deg/dis/xs, esrc fill
__global__ void csr2_kernel(const int* __restrict__ bbase, const int* __restrict__ gcnt,
                            const unsigned int* __restrict__ epack,
                            const float* __restrict__ x, int* __restrict__ deg,
                            int* __restrict__ rowptr, float* __restrict__ dis,
                            float* __restrict__ xs, unsigned short* __restrict__ esrc,
                            int N) {
  __shared__ int lcnt[256];
  __shared__ int lcur[256];
  __shared__ int wsum[4];
  int tid = threadIdx.x, b = blockIdx.x;
  int lane = tid & 63, wid = tid >> 6;
  lcnt[tid] = 0;
  __syncthreads();
  int be0 = bbase[b];
  int be1 = be0 + gcnt[b];
  for (int i = be0 + tid; i < be1; i += 256) atomicAdd(&lcnt[epack[i] & 255u], 1);
  __syncthreads();
  int v = lcnt[tid];
  int inc = wave_iscan(v, lane);
  if (lane == 63) wsum[wid] = inc;
  __syncthreads();
  if (tid == 0) {
    int a = be0;
#pragma unroll
    for (int w = 0; w < 4; ++w) { int t = wsum[w]; wsum[w] = a; a += t; }
  }
  __syncthreads();
  int exc = inc - v + wsum[wid];
  lcur[tid] = exc;
  int node = (b << 8) + tid;
  if (node < N) {
    rowptr[node] = exc;
    deg[node] = v;
    float di = rsqrtf((float)v + 1.0f);  // +1 self loop
    dis[node] = di;
    float4 xv = ((const float4*)x)[node];
    ((float4*)xs)[node] = make_float4(di * xv.x, di * xv.y, di * xv.z, di * xv.w);
  }
  __syncthreads();
  for (int i = be0 + tid; i < be1; i += 256) {
    unsigned int pk = epack[i];
    int pos = atomicAdd(&lcur[pk & 255u], 1);
    esrc[pos] = (unsigned short)(pk >> 8);
  }
}

// ---- layer 1 fused: wave per node; gather xs; h1p = fp16(dis*relu(a@W1+b1))
__global__ void __launch_bounds__(256, 8)
l1_kernel(const int* __restrict__ rowptr, const int* __restrict__ deg,
          const unsigned short* __restrict__ esrc, const float* __restrict__ xs,
          const float* __restrict__ x, const float* __restrict__ dis,
          const float* __restrict__ W1, const float* __restrict__ b1,
          __half* __restrict__ h1p, int N) {
  int tid = threadIdx.x;
  int lane = tid & 63, wid = tid >> 6;
  int d = __builtin_amdgcn_readfirstlane(blockIdx.x * 4 + wid);
  if (d >= N) return;
  float di = dis[d];
  int p = __builtin_amdgcn_readfirstlane(rowptr[d]);
  int n = __builtin_amdgcn_readfirstlane(deg[d]);
  float a0 = 0.f, a1 = 0.f, a2 = 0.f, a3 = 0.f;
  for (int k = lane; k < n; k += 64) {
    int e = esrc[p + k];
    float4 v = ((const float4*)xs)[e];
    a0 += v.x; a1 += v.y; a2 += v.z; a3 += v.w;
  }
  if (lane == 0) {  // self loop: + di*x[d]
    float4 xv = ((const float4*)x)[d];
    a0 = fmaf(di, xv.x, a0); a1 = fmaf(di, xv.y, a1);
    a2 = fmaf(di, xv.z, a2); a3 = fmaf(di, xv.w, a3);
  }
#pragma unroll
  for (int off = 1; off < 64; off <<= 1) {
    a0 += __shfl_xor(a0, off, 64);
    a1 += __shfl_xor(a1, off, 64);
    a2 += __shfl_xor(a2, off, 64);
    a3 += __shfl_xor(a3, off, 64);
  }
  a0 *= di; a1 *= di; a2 *= di; a3 *= di;
  float o = b1[lane] + a0 * W1[lane] + a1 * W1[64 + lane] + a2 * W1[128 + lane] + a3 * W1[192 + lane];
  h1p[(size_t)d * 64 + lane] = __float2half(di * fmaxf(o, 0.0f));
}

// ---- layer 2: grouped row-gather (8 edges/VMEM-round) + matmul + pool ----
__global__ void __launch_bounds__(256, 8)
l2_kernel(const int* __restrict__ rowptr, const int* __restrict__ deg,
          const unsigned short* __restrict__ esrc, const __half* __restrict__ h1p,
          const float* __restrict__ dis, const float* __restrict__ W2,
          const float* __restrict__ b2, const int* __restrict__ batch,
          float* __restrict__ gsum, int N) {
  __shared__ __align__(16) unsigned short ebuf[4][64];
  __shared__ float vbuf[4][64];
  __shared__ float obuf[4][64];
  __shared__ int gbuf[4];
  int tid = threadIdx.x;
  int lane = tid & 63, wid = tid >> 6;
  int g = lane >> 3, c = lane & 7;
  int d0 = blockIdx.x * 4 + wid;
  bool valid = d0 < N;
  int d = __builtin_amdgcn_readfirstlane(valid ? d0 : N - 1);
  float di = dis[d];
  int p = __builtin_amdgcn_readfirstlane(rowptr[d]);
  int n = __builtin_amdgcn_readfirstlane(deg[d]);
  float a0, a1, a2, a3, a4, a5, a6, a7;
  {  // self loop: only group 0 contributes it
    float ms = (g == 0) ? 1.0f : 0.0f;
    uint4 w = *(const uint4*)(h1p + (size_t)d * 64 + 8 * c);
    float2 f0 = __half22float2(*(__half2*)&w.x);
    float2 f1 = __half22float2(*(__half2*)&w.y);
    float2 f2 = __half22float2(*(__half2*)&w.z);
    float2 f3 = __half22float2(*(__half2*)&w.w);
    a0 = ms * f0.x; a1 = ms * f0.y; a2 = ms * f1.x; a3 = ms * f1.y;
    a4 = ms * f2.x; a5 = ms * f2.y; a6 = ms * f3.x; a7 = ms * f3.y;
  }
  for (int base = 0; base < n; base += 64) {
    int m64 = n - base;
    if (m64 > 64) m64 = 64;
    ebuf[wid][lane] = esrc[p + base + ((lane < m64) ? lane : (m64 - 1))];
    for (int k = 0; k < m64; k += 8) {
      int e = ebuf[wid][k + g];              // same-addr broadcast per group
      float m = (k + g < m64) ? 1.0f : 0.0f;
      uint4 w = *(const uint4*)(h1p + (size_t)e * 64 + 8 * c);
      float2 f0 = __half22float2(*(__half2*)&w.x);
      float2 f1 = __half22float2(*(__half2*)&w.y);
      float2 f2 = __half22float2(*(__half2*)&w.z);
      float2 f3 = __half22float2(*(__half2*)&w.w);
      a0 = fmaf(m, f0.x, a0); a1 = fmaf(m, f0.y, a1);
      a2 = fmaf(m, f1.x, a2); a3 = fmaf(m, f1.y, a3);
      a4 = fmaf(m, f2.x, a4); a5 = fmaf(m, f2.y, a5);
      a6 = fmaf(m, f3.x, a6); a7 = fmaf(m, f3.y, a7);
    }
  }
#pragma unroll
  for (int off = 8; off < 64; off <<= 1) {
    a0 += __shfl_xor(a0, off, 64); a1 += __shfl_xor(a1, off, 64);
    a2 += __shfl_xor(a2, off, 64); a3 += __shfl_xor(a3, off, 64);
    a4 += __shfl_xor(a4, off, 64); a5 += __shfl_xor(a5, off, 64);
    a6 += __shfl_xor(a6, off, 64); a7 += __shfl_xor(a7, off, 64);
  }
  if (g == 0) {
    *(float4*)&vbuf[wid][8 * c] = make_float4(di * a0, di * a1, di * a2, di * a3);
    *(float4*)&vbuf[wid][8 * c + 4] = make_float4(di * a4, di * a5, di * a6, di * a7);
  }
  float o = b2[lane];
  const float4* vb4 = (const float4*)vbuf[wid];
#pragma unroll
  for (int kk = 0; kk < 16; ++kk) {
    float4 vv = vb4[kk];
    o = fmaf(vv.x, W2[(kk * 4 + 0) * 64 + lane], o);
    o = fmaf(vv.y, W2[(kk * 4 + 1) * 64 + lane], o);
    o = fmaf(vv.z, W2[(kk * 4 + 2) * 64 + lane], o);
    o = fmaf(vv.w, W2[(kk * 4 + 3) * 64 + lane], o);
  }
  obuf[wid][lane] = fmaxf(o, 0.0f);
  if (lane == 0) gbuf[wid] = valid ? batch[d] : -1;
  __syncthreads();
  if (wid == 0) {
    float s = 0.0f;
    int cur = gbuf[0];
#pragma unroll
    for (int r = 0; r < 4; ++r) {
      int gg = gbuf[r];
      if (gg != cur) {
        if (cur >= 0) atomicAdd(&gsum[cur * 64 + lane], s);
        s = 0.0f;
        cur = gg;
      }
      if (gg >= 0) s += obuf[r][lane];
    }
    if (cur >= 0) atomicAdd(&gsum[cur * 64 + lane], s);
  }
}

// ---- output: mean via binary search on sorted batch ---------------------

__device__ __forceinline__ int lbound(const int* __restrict__ a, int n, int v) {
  int lo = 0, hi = n;
  while (lo < hi) {
    int mid = (lo + hi) >> 1;
    if (a[mid] < v) lo = mid + 1; else hi = mid;
  }
  return lo;
}

__global__ void out_kernel(const float* __restrict__ gsum, const int* __restrict__ batch,
                           int N, float* __restrict__ out) {
  int t = blockIdx.x * blockDim.x + threadIdx.x;
  if (t >= NG * 64) return;
  int g = t >> 6;
  int cnt = lbound(batch, N, g + 1) - lbound(batch, N, g);
  out[t] = gsum[t] / fmaxf((float)cnt, 1.0f);
}

// ---- launch --------------------------------------------------------------

extern "C" void kernel_launch(void* const* d_in, const int* in_sizes, int n_in,
                              void* d_out, int out_size, void* d_ws, size_t ws_size,
                              hipStream_t stream) {
  const float* x = (const float*)d_in[0];
  const int* ei = (const int*)d_in[1];     // [2,E]: src row then dst row
  const int* batch = (const int*)d_in[2];  // sorted graph ids
  const float* W1 = (const float*)d_in[4];
  const float* b1 = (const float*)d_in[5];
  const float* W2 = (const float*)d_in[6];
  const float* b2 = (const float*)d_in[7];

  const int N = in_sizes[0] / 4;           // 50000 (< 65536: ushort esrc ok)
  const int E = in_sizes[1] / 2;
  const int K = (N + 255) >> 8;                 // buckets (dst>>8), <= 256
  const int nblkE = (E + CHUNK - 1) / CHUNK;    // edge chunks
  const int M2 = K * nblkE;

  // ws layout (4B words unless noted):
  // [gsum 8192][gcnt 256] <- zeroed each call
  // [bbase 256][bcur 256][deg N][rowptr N][xs 4N][dis N][h1p 64N halves]
  // [esrc E ushorts][off M2][epack E words]
  float* gsum = (float*)d_ws;
  int* gcnt = (int*)(gsum + 64 * NG);
  int* bbase = gcnt + 256;
  int* bcur = bbase + 256;
  int* deg = bcur + 256;
  int* rowptr = deg + N;
  float* xs = (float*)(rowptr + N);             // (8960+2N)%4==0 -> 16B aligned
  float* dis = xs + (size_t)4 * N;
  __half* h1p = (__half*)(dis + N);
  unsigned short* esrc = (unsigned short*)(dis + N + (size_t)32 * N);
  int* off = (int*)(esrc + E);                  // E even -> 4B aligned
  unsigned int* epack = (unsigned int*)(off + M2);

  hipMemsetAsync(d_ws, 0, (size_t)(64 * NG + 256) * 4, stream);

  const int B = 256;
  hist_kernel<<<nblkE, 256, 0, stream>>>(ei, E, nblkE, K, off, gcnt);
  scanK_kernel<<<1, 256, 0, stream>>>(gcnt, bbase, bcur, K);
  part_kernel<<<nblkE, 256, 0, stream>>>(ei, E, nblkE, K, off, bcur, epack);
  csr2_kernel<<<K, 256, 0, stream>>>(bbase, gcnt, epack, x, deg, rowptr, dis, xs, esrc, N);
  l1_kernel<<<(N + 3) / 4, 256, 0, stream>>>(rowptr, deg, esrc, xs, x, dis, W1, b1, h1p, N);
  l2_kernel<<<(N + 3) / 4, 256, 0, stream>>>(rowptr, deg, esrc, h1p, dis, W2, b2, batch, gsum, N);
  out_kernel<<<(NG * 64 + B - 1) / B, B, 0, stream>>>(gsum, batch, N, (float*)d_out);
}

// Round 25
// 104.390 us; speedup vs baseline: 2.1550x; 1.0178x over previous
//
#include <hip/hip_runtime.h>
#include <hip/hip_fp16.h>

#define NG 128
#define CHUNK 4096

__device__ __forceinline__ int wave_iscan(int v, int lane) {
#pragma unroll
  for (int off = 1; off < 64; off <<= 1) {
    int u = __shfl_up(v, off, 64);
    if (lane >= off) v += u;
  }
  return v;
}

// ---- generic scan helpers (for the off array) ---------------------------

__global__ void bsum_kernel(const int* __restrict__ src, int* __restrict__ bsum, int M) {
  __shared__ int wsum[4];
  int tid = threadIdx.x, lane = tid & 63, wid = tid >> 6;
  int i = blockIdx.x * 256 + tid;
  int v = (i < M) ? src[i] : 0;
  int inc = wave_iscan(v, lane);
  if (lane == 63) wsum[wid] = inc;
  __syncthreads();
  if (tid == 0) bsum[blockIdx.x] = wsum[0] + wsum[1] + wsum[2] + wsum[3];
}

__global__ void bscan_kernel(int* __restrict__ bsum, int nb) {
  __shared__ int wsum[16];
  int tid = threadIdx.x, lane = tid & 63, wid = tid >> 6;
  int v = (tid < nb) ? bsum[tid] : 0;
  int inc = wave_iscan(v, lane);
  if (lane == 63) wsum[wid] = inc;
  __syncthreads();
  if (tid == 0) {
    int a = 0;
#pragma unroll
    for (int w = 0; w < 16; ++w) { int t = wsum[w]; wsum[w] = a; a += t; }
  }
  __syncthreads();
  if (tid < nb) bsum[tid] = inc - v + wsum[wid];
}

__global__ void offadd_kernel(int* __restrict__ off, const int* __restrict__ bsum, int M) {
  __shared__ int wsum[4];
  int tid = threadIdx.x, lane = tid & 63, wid = tid >> 6;
  int i = blockIdx.x * 256 + tid;
  int v = (i < M) ? off[i] : 0;
  int inc = wave_iscan(v, lane);
  if (lane == 63) wsum[wid] = inc;
  __syncthreads();
  if (tid == 0) {
    int a = bsum[blockIdx.x];
#pragma unroll
    for (int w = 0; w < 4; ++w) { int t = wsum[w]; wsum[w] = a; a += t; }
  }
  __syncthreads();
  if (i < M) off[i] = inc - v + wsum[wid];
}

// ---- bucketed edge reorder (bucket = dst >> 8) --------------------------

// int4-vectorized dst stream (E and CHUNK are multiples of 4)
__global__ void hist_kernel(const int* __restrict__ ei, int E, int nblkE, int K,
                            int* __restrict__ off) {
  __shared__ int lh[256];
  int tid = threadIdx.x, blk = blockIdx.x;
  lh[tid] = 0;
  __syncthreads();
  int e0 = blk * CHUNK;
  const int4* d4 = (const int4*)(ei + E + e0);
  for (int i = tid; i < CHUNK / 4; i += 256) {
    int base = e0 + 4 * i;
    if (base + 3 < E) {
      int4 d = d4[i];
      atomicAdd(&lh[d.x >> 8], 1);
      atomicAdd(&lh[d.y >> 8], 1);
      atomicAdd(&lh[d.z >> 8], 1);
      atomicAdd(&lh[d.w >> 8], 1);
    } else {
#pragma unroll
      for (int j = 0; j < 4; ++j) {
        int e = base + j;
        if (e < E) atomicAdd(&lh[ei[E + e] >> 8], 1);
      }
    }
  }
  __syncthreads();
  if (tid < K) off[tid * nblkE + blk] = lh[tid];
}

// partition: epack = (src<<8)|(dst&255) into per-(chunk,bucket) runs
__global__ void part_kernel(const int* __restrict__ ei, int E, int nblkE, int K,
                            const int* __restrict__ off, unsigned int* __restrict__ epack) {
  __shared__ int lcur[256];
  int tid = threadIdx.x, blk = blockIdx.x;
  if (tid < K) lcur[tid] = off[tid * nblkE + blk];
  __syncthreads();
  int e0 = blk * CHUNK;
  const int4* s4 = (const int4*)(ei + e0);
  const int4* d4 = (const int4*)(ei + E + e0);
  for (int i = tid; i < CHUNK / 4; i += 256) {
    int base = e0 + 4 * i;
    if (base + 3 < E) {
      int4 s = s4[i];
      int4 d = d4[i];
#pragma unroll
      for (int j = 0; j < 4; ++j) {
        unsigned int ss = (unsigned int)((j == 0) ? s.x : (j == 1) ? s.y : (j == 2) ? s.z : s.w);
        unsigned int dd = (unsigned int)((j == 0) ? d.x : (j == 1) ? d.y : (j == 2) ? d.z : d.w);
        int pos = atomicAdd(&lcur[dd >> 8], 1);
        epack[pos] = (ss << 8) | (dd & 255u);
      }
    } else {
#pragma unroll
      for (int j = 0; j < 4; ++j) {
        int e = base + j;
        if (e < E) {
          unsigned int ss = (unsigned int)ei[e], dd = (unsigned int)ei[E + e];
          int pos = atomicAdd(&lcur[dd >> 8], 1);
          epack[pos] = (ss << 8) | (dd & 255u);
        }
      }
    }
  }
}

// one block per bucket: degree count + scan -> rowptr/deg/dis/xs, esrc fill
__global__ void csr2_kernel(const int* __restrict__ off, int nblkE, int K,
                            const unsigned int* __restrict__ epack,
                            const float* __restrict__ x, int* __restrict__ deg,
                            int* __restrict__ rowptr, float* __restrict__ dis,
                            float* __restrict__ xs, unsigned short* __restrict__ esrc,
                            int N, int E) {
  __shared__ int lcnt[256];
  __shared__ int lcur[256];
  __shared__ int wsum[4];
  int tid = threadIdx.x, b = blockIdx.x;
  int lane = tid & 63, wid = tid >> 6;
  lcnt[tid] = 0;
  __syncthreads();
  int be0 = off[b * nblkE];
  int be1 = (b + 1 < K) ? off[(b + 1) * nblkE] : E;
  for (int i = be0 + tid; i < be1; i += 256) atomicAdd(&lcnt[epack[i] & 255u], 1);
  __syncthreads();
  int v = lcnt[tid];
  int inc = wave_iscan(v, lane);
  if (lane == 63) wsum[wid] = inc;
  __syncthreads();
  if (tid == 0) {
    int a = be0;
#pragma unroll
    for (int w = 0; w < 4; ++w) { int t = wsum[w]; wsum[w] = a; a += t; }
  }
  __syncthreads();
  int exc = inc - v + wsum[wid];
  lcur[tid] = exc;
  int node = (b << 8) + tid;
  if (node < N) {
    rowptr[node] = exc;
    deg[node] = v;
    float di = rsqrtf((float)v + 1.0f);  // +1 self loop
    dis[node] = di;
    float4 xv = ((const float4*)x)[node];
    ((float4*)xs)[node] = make_float4(di * xv.x, di * xv.y, di * xv.z, di * xv.w);
  }
  __syncthreads();
  for (int i = be0 + tid; i < be1; i += 256) {
    unsigned int pk = epack[i];
    int pos = atomicAdd(&lcur[pk & 255u], 1);
    esrc[pos] = (unsigned short)(pk >> 8);
  }
}

// ---- layer 1 fused: wave per node; gather xs; h1p = fp16(dis*relu(a@W1+b1))
__global__ void __launch_bounds__(256, 8)
l1_kernel(const int* __restrict__ rowptr, const int* __restrict__ deg,
          const unsigned short* __restrict__ esrc, const float* __restrict__ xs,
          const float* __restrict__ x, const float* __restrict__ dis,
          const float* __restrict__ W1, const float* __restrict__ b1,
          __half* __restrict__ h1p, int N) {
  int tid = threadIdx.x;
  int lane = tid & 63, wid = tid >> 6;
  int d = __builtin_amdgcn_readfirstlane(blockIdx.x * 4 + wid);
  if (d >= N) return;
  float di = dis[d];
  int p = __builtin_amdgcn_readfirstlane(rowptr[d]);
  int n = __builtin_amdgcn_readfirstlane(deg[d]);
  float a0 = 0.f, a1 = 0.f, a2 = 0.f, a3 = 0.f;
  for (int k = lane; k < n; k += 64) {
    int e = esrc[p + k];
    float4 v = ((const float4*)xs)[e];
    a0 += v.x; a1 += v.y; a2 += v.z; a3 += v.w;
  }
  if (lane == 0) {  // self loop: + di*x[d]
    float4 xv = ((const float4*)x)[d];
    a0 = fmaf(di, xv.x, a0); a1 = fmaf(di, xv.y, a1);
    a2 = fmaf(di, xv.z, a2); a3 = fmaf(di, xv.w, a3);
  }
#pragma unroll
  for (int off = 1; off < 64; off <<= 1) {
    a0 += __shfl_xor(a0, off, 64);
    a1 += __shfl_xor(a1, off, 64);
    a2 += __shfl_xor(a2, off, 64);
    a3 += __shfl_xor(a3, off, 64);
  }
  a0 *= di; a1 *= di; a2 *= di; a3 *= di;
  float o = b1[lane] + a0 * W1[lane] + a1 * W1[64 + lane] + a2 * W1[128 + lane] + a3 * W1[192 + lane];
  h1p[(size_t)d * 64 + lane] = __float2half(di * fmaxf(o, 0.0f));
}

// ---- layer 2: grouped row-gather (8 edges/VMEM-round) + matmul + pool ----
// Wave = 8 groups x 8 lanes. Group g owns edge slot g; lane c in group loads
// 8 fp16 features (16B uint4) of that edge's row. ~2-3 gather rounds/node.
__global__ void __launch_bounds__(256, 8)
l2_kernel(const int* __restrict__ rowptr, const int* __restrict__ deg,
          const unsigned short* __restrict__ esrc, const __half* __restrict__ h1p,
          const float* __restrict__ dis, const float* __restrict__ W2,
          const float* __restrict__ b2, const int* __restrict__ batch,
          float* __restrict__ gsum, int N) {
  __shared__ __align__(16) unsigned short ebuf[4][64];
  __shared__ float vbuf[4][64];
  __shared__ float obuf[4][64];
  __shared__ int gbuf[4];
  int tid = threadIdx.x;
  int lane = tid & 63, wid = tid >> 6;
  int g = lane >> 3, c = lane & 7;
  int d0 = blockIdx.x * 4 + wid;
  bool valid = d0 < N;
  int d = __builtin_amdgcn_readfirstlane(valid ? d0 : N - 1);
  float di = dis[d];
  int p = __builtin_amdgcn_readfirstlane(rowptr[d]);
  int n = __builtin_amdgcn_readfirstlane(deg[d]);
  float a0, a1, a2, a3, a4, a5, a6, a7;
  {  // self loop: only group 0 contributes it
    float ms = (g == 0) ? 1.0f : 0.0f;
    uint4 w = *(const uint4*)(h1p + (size_t)d * 64 + 8 * c);
    float2 f0 = __half22float2(*(__half2*)&w.x);
    float2 f1 = __half22float2(*(__half2*)&w.y);
    float2 f2 = __half22float2(*(__half2*)&w.z);
    float2 f3 = __half22float2(*(__half2*)&w.w);
    a0 = ms * f0.x; a1 = ms * f0.y; a2 = ms * f1.x; a3 = ms * f1.y;
    a4 = ms * f2.x; a5 = ms * f2.y; a6 = ms * f3.x; a7 = ms * f3.y;
  }
  for (int base = 0; base < n; base += 64) {
    int m64 = n - base;
    if (m64 > 64) m64 = 64;
    // one coalesced VMEM: wave's next <=64 edge indices -> LDS (clamped)
    ebuf[wid][lane] = esrc[p + base + ((lane < m64) ? lane : (m64 - 1))];
    for (int k = 0; k < m64; k += 8) {
      int e = ebuf[wid][k + g];              // same-addr broadcast per group
      float m = (k + g < m64) ? 1.0f : 0.0f;
      uint4 w = *(const uint4*)(h1p + (size_t)e * 64 + 8 * c);
      float2 f0 = __half22float2(*(__half2*)&w.x);
      float2 f1 = __half22float2(*(__half2*)&w.y);
      float2 f2 = __half22float2(*(__half2*)&w.z);
      float2 f3 = __half22float2(*(__half2*)&w.w);
      a0 = fmaf(m, f0.x, a0); a1 = fmaf(m, f0.y, a1);
      a2 = fmaf(m, f1.x, a2); a3 = fmaf(m, f1.y, a3);
      a4 = fmaf(m, f2.x, a4); a5 = fmaf(m, f2.y, a5);
      a6 = fmaf(m, f3.x, a6); a7 = fmaf(m, f3.y, a7);
    }
  }
  // combine the 8 edge groups (lane bits 3..5)
#pragma unroll
  for (int off = 8; off < 64; off <<= 1) {
    a0 += __shfl_xor(a0, off, 64); a1 += __shfl_xor(a1, off, 64);
    a2 += __shfl_xor(a2, off, 64); a3 += __shfl_xor(a3, off, 64);
    a4 += __shfl_xor(a4, off, 64); a5 += __shfl_xor(a5, off, 64);
    a6 += __shfl_xor(a6, off, 64); a7 += __shfl_xor(a7, off, 64);
  }
  if (g == 0) {  // lanes 0..7 hold feature chunks; write v to LDS
    *(float4*)&vbuf[wid][8 * c] = make_float4(di * a0, di * a1, di * a2, di * a3);
    *(float4*)&vbuf[wid][8 * c + 4] = make_float4(di * a4, di * a5, di * a6, di * a7);
  }
  // intra-wave LDS write->read, in-order; no barrier needed
  float o = b2[lane];
  const float4* vb4 = (const float4*)vbuf[wid];
#pragma unroll
  for (int kk = 0; kk < 16; ++kk) {
    float4 vv = vb4[kk];  // uniform address -> broadcast read
    o = fmaf(vv.x, W2[(kk * 4 + 0) * 64 + lane], o);
    o = fmaf(vv.y, W2[(kk * 4 + 1) * 64 + lane], o);
    o = fmaf(vv.z, W2[(kk * 4 + 2) * 64 + lane], o);
    o = fmaf(vv.w, W2[(kk * 4 + 3) * 64 + lane], o);
  }
  obuf[wid][lane] = fmaxf(o, 0.0f);
  if (lane == 0) gbuf[wid] = valid ? batch[d] : -1;
  __syncthreads();
  if (wid == 0) {
    float s = 0.0f;
    int cur = gbuf[0];
#pragma unroll
    for (int r = 0; r < 4; ++r) {
      int gg = gbuf[r];
      if (gg != cur) {
        if (cur >= 0) atomicAdd(&gsum[cur * 64 + lane], s);
        s = 0.0f;
        cur = gg;
      }
      if (gg >= 0) s += obuf[r][lane];
    }
    if (cur >= 0) atomicAdd(&gsum[cur * 64 + lane], s);
  }
}

// ---- output: mean via binary search on sorted batch ---------------------

__device__ __forceinline__ int lbound(const int* __restrict__ a, int n, int v) {
  int lo = 0, hi = n;
  while (lo < hi) {
    int mid = (lo + hi) >> 1;
    if (a[mid] < v) lo = mid + 1; else hi = mid;
  }
  return lo;
}

__global__ void out_kernel(const float* __restrict__ gsum, const int* __restrict__ batch,
                           int N, float* __restrict__ out) {
  int t = blockIdx.x * blockDim.x + threadIdx.x;
  if (t >= NG * 64) return;
  int g = t >> 6;
  int cnt = lbound(batch, N, g + 1) - lbound(batch, N, g);
  out[t] = gsum[t] / fmaxf((float)cnt, 1.0f);
}

// ---- launch --------------------------------------------------------------

extern "C" void kernel_launch(void* const* d_in, const int* in_sizes, int n_in,
                              void* d_out, int out_size, void* d_ws, size_t ws_size,
                              hipStream_t stream) {
  const float* x = (const float*)d_in[0];
  const int* ei = (const int*)d_in[1];     // [2,E]: src row then dst row
  const int* batch = (const int*)d_in[2];  // sorted graph ids
  const float* W1 = (const float*)d_in[4];
  const float* b1 = (const float*)d_in[5];
  const float* W2 = (const float*)d_in[6];
  const float* b2 = (const float*)d_in[7];

  const int N = in_sizes[0] / 4;           // 50000 (< 65536: ushort esrc ok)
  const int E = in_sizes[1] / 2;
  const int K = (N + 255) >> 8;                 // buckets (dst>>8)
  const int nblkE = (E + CHUNK - 1) / CHUNK;    // edge chunks
  const int M2 = K * nblkE;
  const int NB2 = (M2 + 255) / 256;             // <= 1024

  // ws layout (4B words unless noted):
  // [gsum 8192] <- zeroed
  // [deg N][rowptr N][xs 4N][dis N][h1p 64N halves][esrc E ushorts]
  // [off M2][bsum2 1024][epack E words]
  float* gsum = (float*)d_ws;
  int* deg = (int*)(gsum + 64 * NG);
  int* rowptr = deg + N;
  float* xs = (float*)(rowptr + N);             // (8192+2N)%4==0 -> 16B aligned
  float* dis = xs + (size_t)4 * N;
  __half* h1p = (__half*)(dis + N);
  unsigned short* esrc = (unsigned short*)(dis + N + (size_t)32 * N);
  int* off = (int*)(esrc + E);                  // E even -> 4B aligned
  int* bsum2 = off + M2;
  unsigned int* epack = (unsigned int*)(bsum2 + 1024);

  hipMemsetAsync(d_ws, 0, (size_t)64 * NG * 4, stream);

  const int B = 256;
  hist_kernel<<<nblkE, 256, 0, stream>>>(ei, E, nblkE, K, off);
  bsum_kernel<<<NB2, 256, 0, stream>>>(off, bsum2, M2);
  bscan_kernel<<<1, 1024, 0, stream>>>(bsum2, NB2);
  offadd_kernel<<<NB2, 256, 0, stream>>>(off, bsum2, M2);
  part_kernel<<<nblkE, 256, 0, stream>>>(ei, E, nblkE, K, off, epack);
  csr2_kernel<<<K, 256, 0, stream>>>(off, nblkE, K, epack, x, deg, rowptr, dis, xs, esrc, N, E);
  l1_kernel<<<(N + 3) / 4, 256, 0, stream>>>(rowptr, deg, esrc, xs, x, dis, W1, b1, h1p, N);
  l2_kernel<<<(N + 3) / 4, 256, 0, stream>>>(rowptr, deg, esrc, h1p, dis, W2, b2, batch, gsum, N);
  out_kernel<<<(NG * 64 + B - 1) / B, B, 0, stream>>>(gsum, batch, N, (float*)d_out);
}